// Round 7
// baseline (189.513 us; speedup 1.0000x reference)
//
#include <hip/hip_runtime.h>
#include <cstdint>
#include <cstddef>

#define DIM 128
#define HEADS 4

typedef __attribute__((ext_vector_type(8))) short bf16x8;
typedef __attribute__((ext_vector_type(4))) float f32x4;

__device__ __forceinline__ ushort f2bf(float x) {
    union { float f; uint32_t u; } v; v.f = x;
    uint32_t r = v.u + 0x7FFFu + ((v.u >> 16) & 1u);   // RNE
    return (ushort)(r >> 16);
}
__device__ __forceinline__ float bf2f(ushort h) {
    union { uint32_t u; float f; } v; v.u = ((uint32_t)h) << 16; return v.f;
}

// ---------------------------------------------------------------------------
// prep: fused wtrans (blocks 0..191) + count_degree (blocks 192..)
// wtrans: W[k][col] f32 -> Wt[w][col][k] bf16 hi/lo (transposed for B-frags)
// ---------------------------------------------------------------------------
__global__ __launch_bounds__(256)
void prep(const float* __restrict__ qW, const float* __restrict__ kW,
          const float* __restrict__ vW,
          ushort* __restrict__ WtHi, ushort* __restrict__ WtLo,
          const int* __restrict__ rows, int* __restrict__ degree, int E)
{
    int b = blockIdx.x;
    if (b < 192) {
        int t = b * 256 + threadIdx.x;           // 0..49151
        int w = t >> 14;
        int rem = t & 16383;
        int col = rem >> 7;
        int k = rem & 127;
        const float* W = (w == 0) ? qW : (w == 1) ? kW : vW;
        float x = W[k * DIM + col];
        ushort hi = f2bf(x);
        ushort lo = f2bf(x - bf2f(hi));
        WtHi[t] = hi;                            // [w][col][k]
        WtLo[t] = lo;
    } else {
        int e = (b - 192) * 256 + threadIdx.x;
        if (e < E) atomicAdd(&degree[rows[e]], 1);
    }
}

// ---------------------------------------------------------------------------
// qkv_fused v2: Q,K,V = emb @ {qW,kW,vW}, 3-term hi/lo bf16 MFMA, one dispatch.
// 1024 threads = 16 waves (wm: 2 x 64-row halves, wn: 8 x 16-col groups).
// Block = 128 rows x 128 cols x all 3 W -> A converted f32->hi/lo ONCE.
// K in 2 chunks of 64 (128B LDS rows, XOR-swizzle byte^=(row&7)<<4: staging
// stores and frag reads all <=2-way = conflict-free). B staged per (w,chunk)
// into one 32KB buffer; A-frags kept in registers across the w-loop.
// LDS = 64KB exactly -> 2 blocks/CU. Per-acc MFMA k-order ascending with
// (hh,lh,hl) per 32-k slice -> bit-exact vs R5.
// ---------------------------------------------------------------------------
__global__ __launch_bounds__(1024)
void qkv_fused(const float* __restrict__ emb,
               const ushort* __restrict__ WtHi, const ushort* __restrict__ WtLo,
               ushort* __restrict__ Qb, ushort* __restrict__ KVb, int N)
{
    __shared__ ushort Ahi[128 * 64], Alo[128 * 64];   // 16KB each: 128 rows x 64k
    __shared__ ushort Bhi[128 * 64], Blo[128 * 64];   // 16KB each: 128 cols x 64k

    const int tid = threadIdx.x;
    const int wv = tid >> 6;            // 0..15
    const int ln = tid & 63;
    const int l15 = ln & 15;
    const int l4 = ln >> 4;
    const int wm = wv >> 3;             // 0..1  (64-row half)
    const int wn = wv & 7;              // 0..7  (16-col group)
    const int m0 = blockIdx.x * 128;

    f32x4 acc[3][4] = {};               // [wsel][fr]
    bf16x8 ah[4][2], al[4][2];          // A frags of current chunk [fr][s]

    for (int c = 0; c < 2; c++) {       // K chunk: k = c*64 .. +64
        if (c) __syncthreads();         // protect A LDS from prior readers
        // ---- stage A chunk: 128 rows x 64 k, f32 -> bf16 hi/lo (once) ----
#pragma unroll
        for (int p = 0; p < 2; p++) {
            int idx = tid + p * 1024;           // 0..2047
            int row = idx >> 4;                 // 0..127
            int kg  = idx & 15;                 // float4 index within chunk
            float4 a = make_float4(0.f, 0.f, 0.f, 0.f);
            if (m0 + row < N)
                a = *(const float4*)(emb + (size_t)(m0 + row) * DIM + c * 64 + kg * 4);
            ushort4 h, l;
            h.x = f2bf(a.x); l.x = f2bf(a.x - bf2f(h.x));
            h.y = f2bf(a.y); l.y = f2bf(a.y - bf2f(h.y));
            h.z = f2bf(a.z); l.z = f2bf(a.z - bf2f(h.z));
            h.w = f2bf(a.w); l.w = f2bf(a.w - bf2f(h.w));
            int boff = row * 128 + ((kg * 8) ^ ((row & 7) << 4));
            *(ushort4*)((char*)Ahi + boff) = h;
            *(ushort4*)((char*)Alo + boff) = l;
        }
        __syncthreads();
        // ---- load A frags for this chunk (reused across all 3 W) ----
#pragma unroll
        for (int fr = 0; fr < 4; fr++)
#pragma unroll
            for (int s = 0; s < 2; s++) {
                int row = wm * 64 + fr * 16 + l15;
                int boff = row * 128 + ((s * 64 + l4 * 16) ^ ((row & 7) << 4));
                ah[fr][s] = *(bf16x8*)((char*)Ahi + boff);
                al[fr][s] = *(bf16x8*)((char*)Alo + boff);
            }

        for (int w = 0; w < 3; w++) {
            __syncthreads();            // protect B buffer from prior readers
            // ---- stage B(w,c): 128 cols x 64 k, 1 uint4 hi + lo per thread ----
            {
                int colp = tid >> 3;            // 0..127
                int kg = tid & 7;               // 16B groups
                size_t goff = (size_t)w * 16384 + (size_t)colp * DIM + c * 64 + kg * 8;
                uint4 hv = *(const uint4*)(WtHi + goff);
                uint4 lv = *(const uint4*)(WtLo + goff);
                int boff = colp * 128 + ((kg * 16) ^ ((colp & 7) << 4));
                *(uint4*)((char*)Bhi + boff) = hv;
                *(uint4*)((char*)Blo + boff) = lv;
            }
            __syncthreads();
            // ---- MFMA ----
#pragma unroll
            for (int s = 0; s < 2; s++) {
                int col = wn * 16 + l15;
                int boff = col * 128 + ((s * 64 + l4 * 16) ^ ((col & 7) << 4));
                bf16x8 bh = *(bf16x8*)((char*)Bhi + boff);
                bf16x8 bl = *(bf16x8*)((char*)Blo + boff);
#pragma unroll
                for (int fr = 0; fr < 4; fr++) {
                    acc[w][fr] = __builtin_amdgcn_mfma_f32_16x16x32_bf16(ah[fr][s], bh, acc[w][fr], 0, 0, 0);
                    acc[w][fr] = __builtin_amdgcn_mfma_f32_16x16x32_bf16(al[fr][s], bh, acc[w][fr], 0, 0, 0);
                    acc[w][fr] = __builtin_amdgcn_mfma_f32_16x16x32_bf16(ah[fr][s], bl, acc[w][fr], 0, 0, 0);
                }
            }
        }
    }

    // ---- epilogue: C/D layout col=lane&15, row=(lane>>4)*4+j ----
#pragma unroll
    for (int w = 0; w < 3; w++) {
#pragma unroll
        for (int fr = 0; fr < 4; fr++) {
            int rbase = m0 + wm * 64 + fr * 16 + l4 * 4;
            int col = wn * 16 + l15;
#pragma unroll
            for (int j = 0; j < 4; j++) {
                int r = rbase + j;
                if (r < N) {
                    ushort val = f2bf(acc[w][fr][j]);
                    if (w == 0) Qb[(size_t)r * DIM + col] = val;
                    else        KVb[(size_t)r * 256 + (w - 1) * 128 + col] = val;
                }
            }
        }
    }
}

// ---------------------------------------------------------------------------
// CSR build: exclusive scan of degree -> rowPtr, then permutation fill.
// ---------------------------------------------------------------------------
__global__ __launch_bounds__(256)
void scanA(const int* __restrict__ degree, int* __restrict__ rowPtr,
           int* __restrict__ blockSums, int N)
{
    __shared__ int s[256];
    const int tid = threadIdx.x;
    const int base = blockIdx.x * 1024 + tid * 4;
    int d[4];
    int tsum = 0;
#pragma unroll
    for (int i = 0; i < 4; i++) {
        d[i] = (base + i < N) ? degree[base + i] : 0;
        tsum += d[i];
    }
    s[tid] = tsum;
    __syncthreads();
    for (int off = 1; off < 256; off <<= 1) {
        int v = (tid >= off) ? s[tid - off] : 0;
        __syncthreads();
        s[tid] += v;
        __syncthreads();
    }
    if (tid == 255) blockSums[blockIdx.x] = s[255];
    int running = s[tid] - tsum;
#pragma unroll
    for (int i = 0; i < 4; i++) {
        if (base + i < N) rowPtr[base + i] = running;
        running += d[i];
    }
}

__global__ __launch_bounds__(256)
void scanB(int* __restrict__ blockSums, int nb)
{
    __shared__ int s[256];
    const int tid = threadIdx.x;
    int v = (tid < nb) ? blockSums[tid] : 0;
    s[tid] = v;
    __syncthreads();
    for (int off = 1; off < 256; off <<= 1) {
        int u = (tid >= off) ? s[tid - off] : 0;
        __syncthreads();
        s[tid] += u;
        __syncthreads();
    }
    if (tid < nb) blockSums[tid] = s[tid] - v;
}

__global__ __launch_bounds__(256)
void scanC(int* __restrict__ rowPtr, const int* __restrict__ blockSums,
           int* __restrict__ cursor, int N, int E)
{
    const int tid = threadIdx.x;
    const int base = blockIdx.x * 1024 + tid * 4;
    const int off = blockSums[blockIdx.x];
#pragma unroll
    for (int i = 0; i < 4; i++) {
        int idx = base + i;
        if (idx < N) {
            int v = rowPtr[idx] + off;
            rowPtr[idx] = v;
            cursor[idx] = v;
        }
    }
    if (blockIdx.x == 0 && tid == 0) rowPtr[N] = E;
}

__global__ __launch_bounds__(256)
void fill_perm(const int* __restrict__ rows, const int* __restrict__ cols,
               int* __restrict__ cursor, int* __restrict__ perm,
               int* __restrict__ colsCSR, int E)
{
    int e = blockIdx.x * 256 + threadIdx.x;
    if (e >= E) return;
    int pos = atomicAdd(&cursor[rows[e]], 1);
    perm[pos] = e;
    colsCSR[pos] = cols[e];
}

// ---------------------------------------------------------------------------
// csr_fused: 16 lanes per node (8 dims/lane), 4 nodes per wave.
// Head group = 4 lanes, dot reduce via shfl_xor 1,2. Unroll-2 edge loop.
// ---------------------------------------------------------------------------
__global__ __launch_bounds__(256)
void csr_fused(const ushort* __restrict__ Qb, const ushort* __restrict__ KVb,
               const int* __restrict__ rowPtr, const int* __restrict__ perm,
               const int* __restrict__ colsCSR,
               float* __restrict__ attBuf, float* __restrict__ invNorm,
               float* __restrict__ out, int N)
{
    int t = blockIdx.x * 256 + threadIdx.x;
    int node = t >> 4;
    int lane = t & 15;                  // 16 lanes/node
    if (node >= N) return;

    const int start = rowPtr[node];
    const int end   = rowPtr[node + 1];
    const int h = lane >> 2;            // head (4 lanes each)

    const ushort* qp = Qb + (size_t)node * DIM + lane * 8;
    ushort4 qu0 = *(const ushort4*)(qp);
    ushort4 qu1 = *(const ushort4*)(qp + 4);
    float q[8] = {bf2f(qu0.x), bf2f(qu0.y), bf2f(qu0.z), bf2f(qu0.w),
                  bf2f(qu1.x), bf2f(qu1.y), bf2f(qu1.z), bf2f(qu1.w)};

    float norm = 0.f;
    float acc[8] = {0.f, 0.f, 0.f, 0.f, 0.f, 0.f, 0.f, 0.f};

    int p = start;
    for (; p + 2 <= end; p += 2) {
        int c0 = colsCSR[p];
        int c1 = colsCSR[p + 1];
        int e0 = perm[p];
        int e1 = perm[p + 1];
        const ushort* kv0 = KVb + (size_t)c0 * 256 + lane * 8;
        const ushort* kv1 = KVb + (size_t)c1 * 256 + lane * 8;
        ushort4 k0a = *(const ushort4*)(kv0);
        ushort4 k0b = *(const ushort4*)(kv0 + 4);
        ushort4 v0a = *(const ushort4*)(kv0 + 128);
        ushort4 v0b = *(const ushort4*)(kv0 + 132);
        ushort4 k1a = *(const ushort4*)(kv1);
        ushort4 k1b = *(const ushort4*)(kv1 + 4);
        ushort4 v1a = *(const ushort4*)(kv1 + 128);
        ushort4 v1b = *(const ushort4*)(kv1 + 132);
        float d0 = bf2f(k0a.x) * q[0] + bf2f(k0a.y) * q[1]
                 + bf2f(k0a.z) * q[2] + bf2f(k0a.w) * q[3]
                 + bf2f(k0b.x) * q[4] + bf2f(k0b.y) * q[5]
                 + bf2f(k0b.z) * q[6] + bf2f(k0b.w) * q[7];
        float d1 = bf2f(k1a.x) * q[0] + bf2f(k1a.y) * q[1]
                 + bf2f(k1a.z) * q[2] + bf2f(k1a.w) * q[3]
                 + bf2f(k1b.x) * q[4] + bf2f(k1b.y) * q[5]
                 + bf2f(k1b.z) * q[6] + bf2f(k1b.w) * q[7];
        d0 += __shfl_xor(d0, 1, 64);
        d1 += __shfl_xor(d1, 1, 64);
        d0 += __shfl_xor(d0, 2, 64);
        d1 += __shfl_xor(d1, 2, 64);
        d0 = fminf(fmaxf(d0, -10.f), 10.f);
        d1 = fminf(fmaxf(d1, -10.f), 10.f);
        float ex0 = __expf(d0);
        float ex1 = __expf(d1);
        if ((lane & 3) == 0) {
            attBuf[(size_t)e0 * HEADS + h] = ex0;
            attBuf[(size_t)e1 * HEADS + h] = ex1;
        }
        norm += ex0;
        norm += ex1;
        acc[0] += ex0 * bf2f(v0a.x);
        acc[1] += ex0 * bf2f(v0a.y);
        acc[2] += ex0 * bf2f(v0a.z);
        acc[3] += ex0 * bf2f(v0a.w);
        acc[4] += ex0 * bf2f(v0b.x);
        acc[5] += ex0 * bf2f(v0b.y);
        acc[6] += ex0 * bf2f(v0b.z);
        acc[7] += ex0 * bf2f(v0b.w);
        acc[0] += ex1 * bf2f(v1a.x);
        acc[1] += ex1 * bf2f(v1a.y);
        acc[2] += ex1 * bf2f(v1a.z);
        acc[3] += ex1 * bf2f(v1a.w);
        acc[4] += ex1 * bf2f(v1b.x);
        acc[5] += ex1 * bf2f(v1b.y);
        acc[6] += ex1 * bf2f(v1b.z);
        acc[7] += ex1 * bf2f(v1b.w);
    }
    if (p < end) {
        int c = colsCSR[p];
        int e = perm[p];
        const ushort* kv = KVb + (size_t)c * 256 + lane * 8;
        ushort4 ka = *(const ushort4*)(kv);
        ushort4 kb = *(const ushort4*)(kv + 4);
        ushort4 va = *(const ushort4*)(kv + 128);
        ushort4 vb = *(const ushort4*)(kv + 132);
        float d = bf2f(ka.x) * q[0] + bf2f(ka.y) * q[1]
                + bf2f(ka.z) * q[2] + bf2f(ka.w) * q[3]
                + bf2f(kb.x) * q[4] + bf2f(kb.y) * q[5]
                + bf2f(kb.z) * q[6] + bf2f(kb.w) * q[7];
        d += __shfl_xor(d, 1, 64);
        d += __shfl_xor(d, 2, 64);
        d = fminf(fmaxf(d, -10.f), 10.f);
        float ex = __expf(d);
        if ((lane & 3) == 0) attBuf[(size_t)e * HEADS + h] = ex;
        norm += ex;
        acc[0] += ex * bf2f(va.x);
        acc[1] += ex * bf2f(va.y);
        acc[2] += ex * bf2f(va.z);
        acc[3] += ex * bf2f(va.w);
        acc[4] += ex * bf2f(vb.x);
        acc[5] += ex * bf2f(vb.y);
        acc[6] += ex * bf2f(vb.z);
        acc[7] += ex * bf2f(vb.w);
    }

    float inv = 1.f / (norm + 1e-8f);
    if ((lane & 3) == 0) invNorm[(size_t)node * HEADS + h] = inv;
    float* op = out + (size_t)node * DIM + lane * 8;
    *(float4*)(op)     = make_float4(acc[0] * inv, acc[1] * inv,
                                     acc[2] * inv, acc[3] * inv);
    *(float4*)(op + 4) = make_float4(acc[4] * inv, acc[5] * inv,
                                     acc[6] * inv, acc[7] * inv);
}

// ---------------------------------------------------------------------------
// att_scale: attBuf[e][h] *= invNorm[rows[e]][h]   (finishes softmax)
// ---------------------------------------------------------------------------
__global__ __launch_bounds__(256)
void att_scale(float* __restrict__ attBuf, const float* __restrict__ invNorm,
               const int* __restrict__ rows, int E4)
{
    int t = blockIdx.x * 256 + threadIdx.x;
    if (t >= E4) return;
    int e = t >> 2;
    attBuf[t] *= invNorm[(size_t)rows[e] * 4 + (t & 3)];
}

// ---------------------------------------------------------------------------
// kernel_launch
// ws: Qb bf16 [N*128] | KVb bf16 [N*256] | WtHi,WtLo bf16 [3*128*128]*2
//     | invNorm f32 [N*4] | rowPtr[N+1] | blockSums[128] | cursor[N]
//     | perm[E] | colsCSR[E] | degree[N]
// ---------------------------------------------------------------------------
extern "C" void kernel_launch(void* const* d_in, const int* in_sizes, int n_in,
                              void* d_out, int out_size, void* d_ws, size_t ws_size,
                              hipStream_t stream)
{
    const float* emb  = (const float*)d_in[0];
    const float* qW   = (const float*)d_in[1];
    const float* kW   = (const float*)d_in[2];
    const float* vW   = (const float*)d_in[3];
    const int*   rows = (const int*)d_in[4];
    const int*   cols = (const int*)d_in[5];

    const int N = in_sizes[0] / DIM;
    const int E = in_sizes[4];

    float* dout   = (float*)d_out;
    float* outMat = dout;                        // [N,128]
    float* attBuf = dout + (size_t)N * DIM;      // [E,4]

    ushort* Qb   = (ushort*)d_ws;
    ushort* KVb  = Qb + (size_t)N * DIM;
    ushort* WtHi = KVb + (size_t)N * 256;
    ushort* WtLo = WtHi + 3 * DIM * DIM;
    float* invNorm = (float*)(WtLo + 3 * DIM * DIM);
    int* rowPtr    = (int*)(invNorm + (size_t)N * HEADS);
    int* blockSums = rowPtr + (N + 1);
    int* cursor    = blockSums + 128;
    int* perm      = cursor + N;
    int* colsCSR   = perm + E;
    int* degree    = colsCSR + E;

    hipMemsetAsync(degree, 0, (size_t)N * sizeof(int), stream);

    int eblocks = (E + 255) / 256;
    prep<<<192 + eblocks, 256, 0, stream>>>(qW, kW, vW, WtHi, WtLo,
                                            rows, degree, E);

    int gblk = (N + 127) / 128;
    qkv_fused<<<gblk, 1024, 0, stream>>>(emb, WtHi, WtLo, Qb, KVb, N);

    int nb = (N + 1023) / 1024;
    scanA<<<nb, 256, 0, stream>>>(degree, rowPtr, blockSums, N);
    scanB<<<1, 256, 0, stream>>>(blockSums, nb);
    scanC<<<nb, 256, 0, stream>>>(rowPtr, blockSums, cursor, N, E);

    fill_perm<<<eblocks, 256, 0, stream>>>(rows, cols, cursor, perm, colsCSR, E);

    int gblocks = (N * 16 + 255) / 256;
    csr_fused<<<gblocks, 256, 0, stream>>>(Qb, KVb, rowPtr, perm, colsCSR,
                                           attBuf, invNorm, outMat, N);

    int sblocks = (E * HEADS + 255) / 256;
    att_scale<<<sblocks, 256, 0, stream>>>(attBuf, invNorm, rows, E * HEADS);
}

// Round 8
// 176.885 us; speedup vs baseline: 1.0714x; 1.0714x over previous
//
#include <hip/hip_runtime.h>
#include <cstdint>
#include <cstddef>

#define DIM 128
#define HEADS 4

typedef __attribute__((ext_vector_type(8))) short bf16x8;
typedef __attribute__((ext_vector_type(4))) float f32x4;

__device__ __forceinline__ ushort f2bf(float x) {
    union { float f; uint32_t u; } v; v.f = x;
    uint32_t r = v.u + 0x7FFFu + ((v.u >> 16) & 1u);   // RNE
    return (ushort)(r >> 16);
}
__device__ __forceinline__ float bf2f(ushort h) {
    union { uint32_t u; float f; } v; v.u = ((uint32_t)h) << 16; return v.f;
}

// ---------------------------------------------------------------------------
// prep: fused wtrans (blocks 0..191) + count_degree (blocks 192..)
// wtrans: W[k][col] f32 -> Wt in MFMA-FRAGMENT order, bf16 hi/lo:
//   t = ((w*4 + c)*8 + g)*512 + ln*8 + j
//   col = g*16 + (ln&15),  k = c*32 + (ln>>4)*8 + j
// so a wave's B-fragment load for (w, chunk c, colgroup g) is 64 lanes x 16B
// CONTIGUOUS (1KB) directly from global -> no B LDS staging needed in GEMM.
// ---------------------------------------------------------------------------
__global__ __launch_bounds__(256)
void prep(const float* __restrict__ qW, const float* __restrict__ kW,
          const float* __restrict__ vW,
          ushort* __restrict__ WtHi, ushort* __restrict__ WtLo,
          const int* __restrict__ rows, int* __restrict__ degree, int E)
{
    int b = blockIdx.x;
    if (b < 192) {
        int t = b * 256 + threadIdx.x;           // 0..49151
        int j  = t & 7;
        int ln = (t >> 3) & 63;
        int g  = (t >> 9) & 7;
        int c  = (t >> 12) & 3;
        int w  = t >> 14;
        const float* W = (w == 0) ? qW : (w == 1) ? kW : vW;
        int col = g * 16 + (ln & 15);
        int k   = c * 32 + ((ln >> 4) << 3) + j;
        float x = W[k * DIM + col];
        ushort hi = f2bf(x);
        ushort lo = f2bf(x - bf2f(hi));
        WtHi[t] = hi;
        WtLo[t] = lo;
    } else {
        int e = (b - 192) * 256 + threadIdx.x;
        if (e < E) atomicAdd(&degree[rows[e]], 1);
    }
}

// ---------------------------------------------------------------------------
// qkv_fused v3: Q,K,V = emb @ {qW,kW,vW}, 3-term hi/lo bf16 MFMA, one dispatch.
// R5 structure (256 thr = 4 waves 2Mx2N, 64 rows x 64 cols per block,
// k chunks of 32) but B fragments are read DIRECTLY from the pre-swizzled
// global Wt (L2-resident, coalesced 1KB/wave/frag) -> no B LDS, no B stores,
// LDS = A only (10KB) -> high occupancy. MFMA per-acc term order identical
// to R5 (k ascending; hh, lh, hl per slice) -> bit-exact outputs.
// Epilogue: Q -> Qb[r][128]; K,V interleaved -> KVb[r][256].
// ---------------------------------------------------------------------------
#define APAD 40   // 32 k + 8 pad (ushorts); row stride 80B

__global__ __launch_bounds__(256)
void qkv_fused(const float* __restrict__ emb,
               const ushort* __restrict__ WtHi, const ushort* __restrict__ WtLo,
               ushort* __restrict__ Qb, ushort* __restrict__ KVb, int N)
{
    __shared__ ushort Ahi[64 * APAD], Alo[64 * APAD];   // 5120B each

    const int tid = threadIdx.x;
    const int wv = tid >> 6;
    const int ln = tid & 63;
    const int l15 = ln & 15;
    const int l4 = ln >> 4;
    const int wm = wv >> 1;             // wave row group (32 rows)
    const int wn = wv & 1;              // wave col group (32 cols)
    const int m0 = blockIdx.x * 64;
    const int gbase = blockIdx.y * 4;   // global col-group base (16-col units)

    f32x4 acc[3][2][2] = {};            // [wsel][fr][n]

    for (int c = 0; c < 4; c++) {       // k chunk: k = c*32 .. +32
        if (c) __syncthreads();         // protect A LDS from prior readers
        // ---- stage A chunk: 64 rows x 32 k, f32 -> bf16 hi/lo ----
        {
            int row = tid >> 2;                 // 0..63
            int k8 = (tid & 3) * 8;             // 0,8,16,24
            float4 a0 = make_float4(0.f, 0.f, 0.f, 0.f);
            float4 a1 = a0;
            if (m0 + row < N) {
                const float* src = emb + (size_t)(m0 + row) * DIM + c * 32 + k8;
                a0 = *(const float4*)(src);
                a1 = *(const float4*)(src + 4);
            }
            ushort4 h0, l0, h1, l1;
            h0.x = f2bf(a0.x); l0.x = f2bf(a0.x - bf2f(h0.x));
            h0.y = f2bf(a0.y); l0.y = f2bf(a0.y - bf2f(h0.y));
            h0.z = f2bf(a0.z); l0.z = f2bf(a0.z - bf2f(h0.z));
            h0.w = f2bf(a0.w); l0.w = f2bf(a0.w - bf2f(h0.w));
            h1.x = f2bf(a1.x); l1.x = f2bf(a1.x - bf2f(h1.x));
            h1.y = f2bf(a1.y); l1.y = f2bf(a1.y - bf2f(h1.y));
            h1.z = f2bf(a1.z); l1.z = f2bf(a1.z - bf2f(h1.z));
            h1.w = f2bf(a1.w); l1.w = f2bf(a1.w - bf2f(h1.w));
            int u = row * APAD + k8;
            *(ushort4*)(Ahi + u) = h0; *(ushort4*)(Ahi + u + 4) = h1;
            *(ushort4*)(Alo + u) = l0; *(ushort4*)(Alo + u + 4) = l1;
        }
        __syncthreads();

        // ---- A frags: row = wm*32 + fr*16 + l15, k = l4*8 .. +8 ----
        bf16x8 ah[2], al[2];
#pragma unroll
        for (int fr = 0; fr < 2; fr++) {
            int u = (wm * 32 + fr * 16 + l15) * APAD + l4 * 8;
            ah[fr] = *(bf16x8*)(Ahi + u);
            al[fr] = *(bf16x8*)(Alo + u);
        }
        // ---- B frags direct from pre-swizzled global (L2-resident) ----
#pragma unroll
        for (int w = 0; w < 3; w++) {
#pragma unroll
            for (int n = 0; n < 2; n++) {
                size_t goff = ((size_t)((w * 4 + c) * 8 + gbase + wn * 2 + n)) * 512
                            + (size_t)ln * 8;
                bf16x8 bh = *(const bf16x8*)(WtHi + goff);
                bf16x8 bl = *(const bf16x8*)(WtLo + goff);
#pragma unroll
                for (int fr = 0; fr < 2; fr++) {
                    acc[w][fr][n] = __builtin_amdgcn_mfma_f32_16x16x32_bf16(ah[fr], bh, acc[w][fr][n], 0, 0, 0);
                    acc[w][fr][n] = __builtin_amdgcn_mfma_f32_16x16x32_bf16(al[fr], bh, acc[w][fr][n], 0, 0, 0);
                    acc[w][fr][n] = __builtin_amdgcn_mfma_f32_16x16x32_bf16(ah[fr], bl, acc[w][fr][n], 0, 0, 0);
                }
            }
        }
    }

    // ---- epilogue: C/D layout col=lane&15, row=(lane>>4)*4+j ----
#pragma unroll
    for (int w = 0; w < 3; w++) {
#pragma unroll
        for (int fr = 0; fr < 2; fr++) {
            int rbase = m0 + wm * 32 + fr * 16 + l4 * 4;
#pragma unroll
            for (int n = 0; n < 2; n++) {
                int col = blockIdx.y * 64 + wn * 32 + n * 16 + l15;
#pragma unroll
                for (int j = 0; j < 4; j++) {
                    int r = rbase + j;
                    if (r < N) {
                        ushort val = f2bf(acc[w][fr][n][j]);
                        if (w == 0) Qb[(size_t)r * DIM + col] = val;
                        else        KVb[(size_t)r * 256 + (w - 1) * 128 + col] = val;
                    }
                }
            }
        }
    }
}

// ---------------------------------------------------------------------------
// CSR build: exclusive scan of degree -> rowPtr, then permutation fill.
// ---------------------------------------------------------------------------
__global__ __launch_bounds__(256)
void scanA(const int* __restrict__ degree, int* __restrict__ rowPtr,
           int* __restrict__ blockSums, int N)
{
    __shared__ int s[256];
    const int tid = threadIdx.x;
    const int base = blockIdx.x * 1024 + tid * 4;
    int d[4];
    int tsum = 0;
#pragma unroll
    for (int i = 0; i < 4; i++) {
        d[i] = (base + i < N) ? degree[base + i] : 0;
        tsum += d[i];
    }
    s[tid] = tsum;
    __syncthreads();
    for (int off = 1; off < 256; off <<= 1) {
        int v = (tid >= off) ? s[tid - off] : 0;
        __syncthreads();
        s[tid] += v;
        __syncthreads();
    }
    if (tid == 255) blockSums[blockIdx.x] = s[255];
    int running = s[tid] - tsum;
#pragma unroll
    for (int i = 0; i < 4; i++) {
        if (base + i < N) rowPtr[base + i] = running;
        running += d[i];
    }
}

__global__ __launch_bounds__(256)
void scanB(int* __restrict__ blockSums, int nb)
{
    __shared__ int s[256];
    const int tid = threadIdx.x;
    int v = (tid < nb) ? blockSums[tid] : 0;
    s[tid] = v;
    __syncthreads();
    for (int off = 1; off < 256; off <<= 1) {
        int u = (tid >= off) ? s[tid - off] : 0;
        __syncthreads();
        s[tid] += u;
        __syncthreads();
    }
    if (tid < nb) blockSums[tid] = s[tid] - v;
}

__global__ __launch_bounds__(256)
void scanC(int* __restrict__ rowPtr, const int* __restrict__ blockSums,
           int* __restrict__ cursor, int N, int E)
{
    const int tid = threadIdx.x;
    const int base = blockIdx.x * 1024 + tid * 4;
    const int off = blockSums[blockIdx.x];
#pragma unroll
    for (int i = 0; i < 4; i++) {
        int idx = base + i;
        if (idx < N) {
            int v = rowPtr[idx] + off;
            rowPtr[idx] = v;
            cursor[idx] = v;
        }
    }
    if (blockIdx.x == 0 && tid == 0) rowPtr[N] = E;
}

__global__ __launch_bounds__(256)
void fill_perm(const int* __restrict__ rows, const int* __restrict__ cols,
               int* __restrict__ cursor, int* __restrict__ perm,
               int* __restrict__ colsCSR, int E)
{
    int e = blockIdx.x * 256 + threadIdx.x;
    if (e >= E) return;
    int pos = atomicAdd(&cursor[rows[e]], 1);
    perm[pos] = e;
    colsCSR[pos] = cols[e];
}

// ---------------------------------------------------------------------------
// csr_fused: 8 lanes per node (16 dims/lane), 8 nodes per wave -> 2x the
// independent gather streams of the 16-lane version (avg degree is only 4,
// MLP is the limiter). Head group = 2 lanes, dot reduce via shfl_xor(1).
// Unroll-2 edge loop. Writes ex to attBuf, invNorm per (node,head);
// out = acc*inv written once, coalesced.
// ---------------------------------------------------------------------------
__global__ __launch_bounds__(256)
void csr_fused(const ushort* __restrict__ Qb, const ushort* __restrict__ KVb,
               const int* __restrict__ rowPtr, const int* __restrict__ perm,
               const int* __restrict__ colsCSR,
               float* __restrict__ attBuf, float* __restrict__ invNorm,
               float* __restrict__ out, int N)
{
    int t = blockIdx.x * 256 + threadIdx.x;
    int node = t >> 3;
    int lane = t & 7;                   // 8 lanes/node, 16 dims each
    if (node >= N) return;

    const int start = rowPtr[node];
    const int end   = rowPtr[node + 1];
    const int h = lane >> 1;            // head (2 lanes each)

    const ushort* qp = Qb + (size_t)node * DIM + lane * 16;
    float q[16];
#pragma unroll
    for (int i = 0; i < 4; i++) {
        ushort4 qu = *(const ushort4*)(qp + i * 4);
        q[i * 4 + 0] = bf2f(qu.x);
        q[i * 4 + 1] = bf2f(qu.y);
        q[i * 4 + 2] = bf2f(qu.z);
        q[i * 4 + 3] = bf2f(qu.w);
    }

    float norm = 0.f;
    float acc[16];
#pragma unroll
    for (int i = 0; i < 16; i++) acc[i] = 0.f;

    int p = start;
    for (; p + 2 <= end; p += 2) {
        int c0 = colsCSR[p];
        int c1 = colsCSR[p + 1];
        int e0 = perm[p];
        int e1 = perm[p + 1];
        const ushort* kv0 = KVb + (size_t)c0 * 256 + lane * 16;
        const ushort* kv1 = KVb + (size_t)c1 * 256 + lane * 16;
        ushort4 k0[4], v0[4], k1[4], v1[4];
#pragma unroll
        for (int i = 0; i < 4; i++) {
            k0[i] = *(const ushort4*)(kv0 + i * 4);
            v0[i] = *(const ushort4*)(kv0 + 128 + i * 4);
            k1[i] = *(const ushort4*)(kv1 + i * 4);
            v1[i] = *(const ushort4*)(kv1 + 128 + i * 4);
        }
        float d0 = 0.f, d1 = 0.f;
#pragma unroll
        for (int i = 0; i < 4; i++) {
            d0 += bf2f(k0[i].x) * q[i * 4 + 0] + bf2f(k0[i].y) * q[i * 4 + 1]
                + bf2f(k0[i].z) * q[i * 4 + 2] + bf2f(k0[i].w) * q[i * 4 + 3];
            d1 += bf2f(k1[i].x) * q[i * 4 + 0] + bf2f(k1[i].y) * q[i * 4 + 1]
                + bf2f(k1[i].z) * q[i * 4 + 2] + bf2f(k1[i].w) * q[i * 4 + 3];
        }
        d0 += __shfl_xor(d0, 1, 64);
        d1 += __shfl_xor(d1, 1, 64);
        d0 = fminf(fmaxf(d0, -10.f), 10.f);
        d1 = fminf(fmaxf(d1, -10.f), 10.f);
        float ex0 = __expf(d0);
        float ex1 = __expf(d1);
        if ((lane & 1) == 0) {
            attBuf[(size_t)e0 * HEADS + h] = ex0;
            attBuf[(size_t)e1 * HEADS + h] = ex1;
        }
        norm += ex0;
        norm += ex1;
#pragma unroll
        for (int i = 0; i < 4; i++) {
            acc[i * 4 + 0] += ex0 * bf2f(v0[i].x);
            acc[i * 4 + 1] += ex0 * bf2f(v0[i].y);
            acc[i * 4 + 2] += ex0 * bf2f(v0[i].z);
            acc[i * 4 + 3] += ex0 * bf2f(v0[i].w);
        }
#pragma unroll
        for (int i = 0; i < 4; i++) {
            acc[i * 4 + 0] += ex1 * bf2f(v1[i].x);
            acc[i * 4 + 1] += ex1 * bf2f(v1[i].y);
            acc[i * 4 + 2] += ex1 * bf2f(v1[i].z);
            acc[i * 4 + 3] += ex1 * bf2f(v1[i].w);
        }
    }
    if (p < end) {
        int c = colsCSR[p];
        int e = perm[p];
        const ushort* kv = KVb + (size_t)c * 256 + lane * 16;
        ushort4 ka[4], va[4];
#pragma unroll
        for (int i = 0; i < 4; i++) {
            ka[i] = *(const ushort4*)(kv + i * 4);
            va[i] = *(const ushort4*)(kv + 128 + i * 4);
        }
        float d = 0.f;
#pragma unroll
        for (int i = 0; i < 4; i++) {
            d += bf2f(ka[i].x) * q[i * 4 + 0] + bf2f(ka[i].y) * q[i * 4 + 1]
               + bf2f(ka[i].z) * q[i * 4 + 2] + bf2f(ka[i].w) * q[i * 4 + 3];
        }
        d += __shfl_xor(d, 1, 64);
        d = fminf(fmaxf(d, -10.f), 10.f);
        float ex = __expf(d);
        if ((lane & 1) == 0) attBuf[(size_t)e * HEADS + h] = ex;
        norm += ex;
#pragma unroll
        for (int i = 0; i < 4; i++) {
            acc[i * 4 + 0] += ex * bf2f(va[i].x);
            acc[i * 4 + 1] += ex * bf2f(va[i].y);
            acc[i * 4 + 2] += ex * bf2f(va[i].z);
            acc[i * 4 + 3] += ex * bf2f(va[i].w);
        }
    }

    float inv = 1.f / (norm + 1e-8f);
    if ((lane & 1) == 0) invNorm[(size_t)node * HEADS + h] = inv;
    float* op = out + (size_t)node * DIM + lane * 16;
#pragma unroll
    for (int i = 0; i < 4; i++) {
        *(float4*)(op + i * 4) = make_float4(acc[i * 4 + 0] * inv,
                                             acc[i * 4 + 1] * inv,
                                             acc[i * 4 + 2] * inv,
                                             acc[i * 4 + 3] * inv);
    }
}

// ---------------------------------------------------------------------------
// att_scale: attBuf[e][h] *= invNorm[rows[e]][h]   (finishes softmax)
// ---------------------------------------------------------------------------
__global__ __launch_bounds__(256)
void att_scale(float* __restrict__ attBuf, const float* __restrict__ invNorm,
               const int* __restrict__ rows, int E4)
{
    int t = blockIdx.x * 256 + threadIdx.x;
    if (t >= E4) return;
    int e = t >> 2;
    attBuf[t] *= invNorm[(size_t)rows[e] * 4 + (t & 3)];
}

// ---------------------------------------------------------------------------
// kernel_launch
// ws: Qb bf16 [N*128] | KVb bf16 [N*256] | WtHi,WtLo bf16 [3*128*128]*2
//     | invNorm f32 [N*4] | rowPtr[N+1] | blockSums[128] | cursor[N]
//     | perm[E] | colsCSR[E] | degree[N]
// ---------------------------------------------------------------------------
extern "C" void kernel_launch(void* const* d_in, const int* in_sizes, int n_in,
                              void* d_out, int out_size, void* d_ws, size_t ws_size,
                              hipStream_t stream)
{
    const float* emb  = (const float*)d_in[0];
    const float* qW   = (const float*)d_in[1];
    const float* kW   = (const float*)d_in[2];
    const float* vW   = (const float*)d_in[3];
    const int*   rows = (const int*)d_in[4];
    const int*   cols = (const int*)d_in[5];

    const int N = in_sizes[0] / DIM;
    const int E = in_sizes[4];

    float* dout   = (float*)d_out;
    float* outMat = dout;                        // [N,128]
    float* attBuf = dout + (size_t)N * DIM;      // [E,4]

    ushort* Qb   = (ushort*)d_ws;
    ushort* KVb  = Qb + (size_t)N * DIM;
    ushort* WtHi = KVb + (size_t)N * 256;
    ushort* WtLo = WtHi + 3 * DIM * DIM;
    float* invNorm = (float*)(WtLo + 3 * DIM * DIM);
    int* rowPtr    = (int*)(invNorm + (size_t)N * HEADS);
    int* blockSums = rowPtr + (N + 1);
    int* cursor    = blockSums + 128;
    int* perm      = cursor + N;
    int* colsCSR   = perm + E;
    int* degree    = colsCSR + E;

    hipMemsetAsync(degree, 0, (size_t)N * sizeof(int), stream);

    int eblocks = (E + 255) / 256;
    prep<<<192 + eblocks, 256, 0, stream>>>(qW, kW, vW, WtHi, WtLo,
                                            rows, degree, E);

    dim3 ggrid((N + 63) / 64, 2);
    qkv_fused<<<ggrid, 256, 0, stream>>>(emb, WtHi, WtLo, Qb, KVb, N);

    int nb = (N + 1023) / 1024;
    scanA<<<nb, 256, 0, stream>>>(degree, rowPtr, blockSums, N);
    scanB<<<1, 256, 0, stream>>>(blockSums, nb);
    scanC<<<nb, 256, 0, stream>>>(rowPtr, blockSums, cursor, N, E);

    fill_perm<<<eblocks, 256, 0, stream>>>(rows, cols, cursor, perm, colsCSR, E);

    int gblocks = (N * 8 + 255) / 256;
    csr_fused<<<gblocks, 256, 0, stream>>>(Qb, KVb, rowPtr, perm, colsCSR,
                                           attBuf, invNorm, outMat, N);

    int sblocks = (E * HEADS + 255) / 256;
    att_scale<<<sblocks, 256, 0, stream>>>(attBuf, invNorm, rows, E * HEADS);
}

// Round 9
// 176.086 us; speedup vs baseline: 1.0763x; 1.0045x over previous
//
#include <hip/hip_runtime.h>
#include <cstdint>
#include <cstddef>

#define DIM 128
#define HEADS 4

typedef __attribute__((ext_vector_type(8))) short bf16x8;
typedef __attribute__((ext_vector_type(4))) float f32x4;

__device__ __forceinline__ ushort f2bf(float x) {
    union { float f; uint32_t u; } v; v.f = x;
    uint32_t r = v.u + 0x7FFFu + ((v.u >> 16) & 1u);   // RNE
    return (ushort)(r >> 16);
}
__device__ __forceinline__ float bf2f(ushort h) {
    union { uint32_t u; float f; } v; v.u = ((uint32_t)h) << 16; return v.f;
}

// ---------------------------------------------------------------------------
// prep: fused wtrans (blocks 0..191) + count_degree (blocks 192..)
// wtrans: W[k][col] f32 -> Wt in MFMA-FRAGMENT order, bf16 hi/lo:
//   t = ((w*4 + c)*8 + g)*512 + ln*8 + j
//   col = g*16 + (ln&15),  k = c*32 + (ln>>4)*8 + j
// so a wave's B-fragment load for (w, chunk c, colgroup g) is 64 lanes x 16B
// CONTIGUOUS (1KB) directly from global -> no B LDS staging needed in GEMM.
// ---------------------------------------------------------------------------
__global__ __launch_bounds__(256)
void prep(const float* __restrict__ qW, const float* __restrict__ kW,
          const float* __restrict__ vW,
          ushort* __restrict__ WtHi, ushort* __restrict__ WtLo,
          const int* __restrict__ rows, int* __restrict__ degree, int E)
{
    int b = blockIdx.x;
    if (b < 192) {
        int t = b * 256 + threadIdx.x;           // 0..49151
        int j  = t & 7;
        int ln = (t >> 3) & 63;
        int g  = (t >> 9) & 7;
        int c  = (t >> 12) & 3;
        int w  = t >> 14;
        const float* W = (w == 0) ? qW : (w == 1) ? kW : vW;
        int col = g * 16 + (ln & 15);
        int k   = c * 32 + ((ln >> 4) << 3) + j;
        float x = W[k * DIM + col];
        ushort hi = f2bf(x);
        ushort lo = f2bf(x - bf2f(hi));
        WtHi[t] = hi;
        WtLo[t] = lo;
    } else {
        int e = (b - 192) * 256 + threadIdx.x;
        if (e < E) atomicAdd(&degree[rows[e]], 1);
    }
}

// ---------------------------------------------------------------------------
// qkv_fused v4: Q,K,V = emb @ {qW,kW,vW}, 3-term hi/lo bf16 MFMA, one dispatch.
// 256 thr = 4 waves (2M x 2N), block = 64 rows x 64 cols (blockIdx.y = half).
// FULL-K A tile (64 x 128) staged hi/lo ONCE -> ONE barrier total; the whole
// MFMA phase (LDS A-frag reads + direct pre-swizzled-global B reads + MFMA)
// is barrier-free so waves free-run and overlap loads with compute.
// XOR swizzle byte^=(row&7)<<4 on 256B LDS rows: stores & reads <=2-way (free).
// LDS = 32KB -> 5 blocks/CU. MFMA per-acc term order identical to R5
// (k ascending; hh, lh, hl per 32-k slice) -> bit-exact outputs.
// Epilogue: Q -> Qb[r][128]; K,V interleaved -> KVb[r][256].
// ---------------------------------------------------------------------------
__global__ __launch_bounds__(256)
void qkv_fused(const float* __restrict__ emb,
               const ushort* __restrict__ WtHi, const ushort* __restrict__ WtLo,
               ushort* __restrict__ Qb, ushort* __restrict__ KVb, int N)
{
    __shared__ ushort Ahi[64 * 128];   // 16KB, row stride 256B, XOR-swizzled
    __shared__ ushort Alo[64 * 128];   // 16KB

    const int tid = threadIdx.x;
    const int wv = tid >> 6;
    const int ln = tid & 63;
    const int l15 = ln & 15;
    const int l4 = ln >> 4;
    const int wm = wv >> 1;             // wave row group (32 rows)
    const int wn = wv & 1;              // wave col group (32 cols)
    const int m0 = blockIdx.x * 64;
    const int gbase = blockIdx.y * 4;   // global col-group base (16-col units)

    // ---- stage full-K A tile: 64 rows x 128 k, f32 -> bf16 hi/lo, once ----
#pragma unroll
    for (int p = 0; p < 8; p++) {
        int idx = tid + p * 256;            // 0..2047
        int row = idx >> 5;                 // 0..63
        int kg  = idx & 31;                 // float4 group: k = kg*4
        float4 a = make_float4(0.f, 0.f, 0.f, 0.f);
        if (m0 + row < N)
            a = *(const float4*)(emb + (size_t)(m0 + row) * DIM + kg * 4);
        ushort4 h, l;
        h.x = f2bf(a.x); l.x = f2bf(a.x - bf2f(h.x));
        h.y = f2bf(a.y); l.y = f2bf(a.y - bf2f(h.y));
        h.z = f2bf(a.z); l.z = f2bf(a.z - bf2f(h.z));
        h.w = f2bf(a.w); l.w = f2bf(a.w - bf2f(h.w));
        int boff = row * 256 + ((kg * 8) ^ ((row & 7) << 4));
        *(ushort4*)((char*)Ahi + boff) = h;
        *(ushort4*)((char*)Alo + boff) = l;
    }
    __syncthreads();                        // the ONLY barrier

    f32x4 acc[3][2][2] = {};                // [wsel][fr][n]

    for (int c = 0; c < 4; c++) {           // k chunk: k = c*32 .. +32
        // ---- A frags from LDS: row = wm*32+fr*16+l15, k = c*32+l4*8 ----
        bf16x8 ah[2], al[2];
#pragma unroll
        for (int fr = 0; fr < 2; fr++) {
            int row = wm * 32 + fr * 16 + l15;
            int boff = row * 256 + ((c * 64 + l4 * 16) ^ ((row & 7) << 4));
            ah[fr] = *(bf16x8*)((char*)Ahi + boff);
            al[fr] = *(bf16x8*)((char*)Alo + boff);
        }
        // ---- B frags direct from pre-swizzled global (L2-resident) ----
#pragma unroll
        for (int w = 0; w < 3; w++) {
#pragma unroll
            for (int n = 0; n < 2; n++) {
                size_t goff = ((size_t)((w * 4 + c) * 8 + gbase + wn * 2 + n)) * 512
                            + (size_t)ln * 8;
                bf16x8 bh = *(const bf16x8*)(WtHi + goff);
                bf16x8 bl = *(const bf16x8*)(WtLo + goff);
#pragma unroll
                for (int fr = 0; fr < 2; fr++) {
                    acc[w][fr][n] = __builtin_amdgcn_mfma_f32_16x16x32_bf16(ah[fr], bh, acc[w][fr][n], 0, 0, 0);
                    acc[w][fr][n] = __builtin_amdgcn_mfma_f32_16x16x32_bf16(al[fr], bh, acc[w][fr][n], 0, 0, 0);
                    acc[w][fr][n] = __builtin_amdgcn_mfma_f32_16x16x32_bf16(ah[fr], bl, acc[w][fr][n], 0, 0, 0);
                }
            }
        }
    }

    // ---- epilogue: C/D layout col=lane&15, row=(lane>>4)*4+j ----
#pragma unroll
    for (int w = 0; w < 3; w++) {
#pragma unroll
        for (int fr = 0; fr < 2; fr++) {
            int rbase = m0 + wm * 32 + fr * 16 + l4 * 4;
#pragma unroll
            for (int n = 0; n < 2; n++) {
                int col = blockIdx.y * 64 + wn * 32 + n * 16 + l15;
#pragma unroll
                for (int j = 0; j < 4; j++) {
                    int r = rbase + j;
                    if (r < N) {
                        ushort val = f2bf(acc[w][fr][n][j]);
                        if (w == 0) Qb[(size_t)r * DIM + col] = val;
                        else        KVb[(size_t)r * 256 + (w - 1) * 128 + col] = val;
                    }
                }
            }
        }
    }
}

// ---------------------------------------------------------------------------
// CSR build: exclusive scan of degree -> rowPtr, then permutation fill.
// ---------------------------------------------------------------------------
__global__ __launch_bounds__(256)
void scanA(const int* __restrict__ degree, int* __restrict__ rowPtr,
           int* __restrict__ blockSums, int N)
{
    __shared__ int s[256];
    const int tid = threadIdx.x;
    const int base = blockIdx.x * 1024 + tid * 4;
    int d[4];
    int tsum = 0;
#pragma unroll
    for (int i = 0; i < 4; i++) {
        d[i] = (base + i < N) ? degree[base + i] : 0;
        tsum += d[i];
    }
    s[tid] = tsum;
    __syncthreads();
    for (int off = 1; off < 256; off <<= 1) {
        int v = (tid >= off) ? s[tid - off] : 0;
        __syncthreads();
        s[tid] += v;
        __syncthreads();
    }
    if (tid == 255) blockSums[blockIdx.x] = s[255];
    int running = s[tid] - tsum;
#pragma unroll
    for (int i = 0; i < 4; i++) {
        if (base + i < N) rowPtr[base + i] = running;
        running += d[i];
    }
}

__global__ __launch_bounds__(256)
void scanB(int* __restrict__ blockSums, int nb)
{
    __shared__ int s[256];
    const int tid = threadIdx.x;
    int v = (tid < nb) ? blockSums[tid] : 0;
    s[tid] = v;
    __syncthreads();
    for (int off = 1; off < 256; off <<= 1) {
        int u = (tid >= off) ? s[tid - off] : 0;
        __syncthreads();
        s[tid] += u;
        __syncthreads();
    }
    if (tid < nb) blockSums[tid] = s[tid] - v;
}

__global__ __launch_bounds__(256)
void scanC(int* __restrict__ rowPtr, const int* __restrict__ blockSums,
           int* __restrict__ cursor, int N, int E)
{
    const int tid = threadIdx.x;
    const int base = blockIdx.x * 1024 + tid * 4;
    const int off = blockSums[blockIdx.x];
#pragma unroll
    for (int i = 0; i < 4; i++) {
        int idx = base + i;
        if (idx < N) {
            int v = rowPtr[idx] + off;
            rowPtr[idx] = v;
            cursor[idx] = v;
        }
    }
    if (blockIdx.x == 0 && tid == 0) rowPtr[N] = E;
}

__global__ __launch_bounds__(256)
void fill_perm(const int* __restrict__ rows, const int* __restrict__ cols,
               int* __restrict__ cursor, int* __restrict__ perm,
               int* __restrict__ colsCSR, int E)
{
    int e = blockIdx.x * 256 + threadIdx.x;
    if (e >= E) return;
    int pos = atomicAdd(&cursor[rows[e]], 1);
    perm[pos] = e;
    colsCSR[pos] = cols[e];
}

// ---------------------------------------------------------------------------
// csr_fused: 16 lanes per node (8 dims/lane), 4 nodes per wave (the R5/R6
// proven sweet spot). Head group = 4 lanes, dot reduce via shfl_xor 1,2.
// Unroll-2 edge loop. Writes ex to attBuf, invNorm per (node,head);
// out = acc*inv written once, coalesced.
// ---------------------------------------------------------------------------
__global__ __launch_bounds__(256)
void csr_fused(const ushort* __restrict__ Qb, const ushort* __restrict__ KVb,
               const int* __restrict__ rowPtr, const int* __restrict__ perm,
               const int* __restrict__ colsCSR,
               float* __restrict__ attBuf, float* __restrict__ invNorm,
               float* __restrict__ out, int N)
{
    int t = blockIdx.x * 256 + threadIdx.x;
    int node = t >> 4;
    int lane = t & 15;                  // 16 lanes/node
    if (node >= N) return;

    const int start = rowPtr[node];
    const int end   = rowPtr[node + 1];
    const int h = lane >> 2;            // head (4 lanes each)

    const ushort* qp = Qb + (size_t)node * DIM + lane * 8;
    ushort4 qu0 = *(const ushort4*)(qp);
    ushort4 qu1 = *(const ushort4*)(qp + 4);
    float q[8] = {bf2f(qu0.x), bf2f(qu0.y), bf2f(qu0.z), bf2f(qu0.w),
                  bf2f(qu1.x), bf2f(qu1.y), bf2f(qu1.z), bf2f(qu1.w)};

    float norm = 0.f;
    float acc[8] = {0.f, 0.f, 0.f, 0.f, 0.f, 0.f, 0.f, 0.f};

    int p = start;
    for (; p + 2 <= end; p += 2) {
        int c0 = colsCSR[p];
        int c1 = colsCSR[p + 1];
        int e0 = perm[p];
        int e1 = perm[p + 1];
        const ushort* kv0 = KVb + (size_t)c0 * 256 + lane * 8;
        const ushort* kv1 = KVb + (size_t)c1 * 256 + lane * 8;
        ushort4 k0a = *(const ushort4*)(kv0);
        ushort4 k0b = *(const ushort4*)(kv0 + 4);
        ushort4 v0a = *(const ushort4*)(kv0 + 128);
        ushort4 v0b = *(const ushort4*)(kv0 + 132);
        ushort4 k1a = *(const ushort4*)(kv1);
        ushort4 k1b = *(const ushort4*)(kv1 + 4);
        ushort4 v1a = *(const ushort4*)(kv1 + 128);
        ushort4 v1b = *(const ushort4*)(kv1 + 132);
        float d0 = bf2f(k0a.x) * q[0] + bf2f(k0a.y) * q[1]
                 + bf2f(k0a.z) * q[2] + bf2f(k0a.w) * q[3]
                 + bf2f(k0b.x) * q[4] + bf2f(k0b.y) * q[5]
                 + bf2f(k0b.z) * q[6] + bf2f(k0b.w) * q[7];
        float d1 = bf2f(k1a.x) * q[0] + bf2f(k1a.y) * q[1]
                 + bf2f(k1a.z) * q[2] + bf2f(k1a.w) * q[3]
                 + bf2f(k1b.x) * q[4] + bf2f(k1b.y) * q[5]
                 + bf2f(k1b.z) * q[6] + bf2f(k1b.w) * q[7];
        d0 += __shfl_xor(d0, 1, 64);
        d1 += __shfl_xor(d1, 1, 64);
        d0 += __shfl_xor(d0, 2, 64);
        d1 += __shfl_xor(d1, 2, 64);
        d0 = fminf(fmaxf(d0, -10.f), 10.f);
        d1 = fminf(fmaxf(d1, -10.f), 10.f);
        float ex0 = __expf(d0);
        float ex1 = __expf(d1);
        if ((lane & 3) == 0) {
            attBuf[(size_t)e0 * HEADS + h] = ex0;
            attBuf[(size_t)e1 * HEADS + h] = ex1;
        }
        norm += ex0;
        norm += ex1;
        acc[0] += ex0 * bf2f(v0a.x);
        acc[1] += ex0 * bf2f(v0a.y);
        acc[2] += ex0 * bf2f(v0a.z);
        acc[3] += ex0 * bf2f(v0a.w);
        acc[4] += ex0 * bf2f(v0b.x);
        acc[5] += ex0 * bf2f(v0b.y);
        acc[6] += ex0 * bf2f(v0b.z);
        acc[7] += ex0 * bf2f(v0b.w);
        acc[0] += ex1 * bf2f(v1a.x);
        acc[1] += ex1 * bf2f(v1a.y);
        acc[2] += ex1 * bf2f(v1a.z);
        acc[3] += ex1 * bf2f(v1a.w);
        acc[4] += ex1 * bf2f(v1b.x);
        acc[5] += ex1 * bf2f(v1b.y);
        acc[6] += ex1 * bf2f(v1b.z);
        acc[7] += ex1 * bf2f(v1b.w);
    }
    if (p < end) {
        int c = colsCSR[p];
        int e = perm[p];
        const ushort* kv = KVb + (size_t)c * 256 + lane * 8;
        ushort4 ka = *(const ushort4*)(kv);
        ushort4 kb = *(const ushort4*)(kv + 4);
        ushort4 va = *(const ushort4*)(kv + 128);
        ushort4 vb = *(const ushort4*)(kv + 132);
        float d = bf2f(ka.x) * q[0] + bf2f(ka.y) * q[1]
                + bf2f(ka.z) * q[2] + bf2f(ka.w) * q[3]
                + bf2f(kb.x) * q[4] + bf2f(kb.y) * q[5]
                + bf2f(kb.z) * q[6] + bf2f(kb.w) * q[7];
        d += __shfl_xor(d, 1, 64);
        d += __shfl_xor(d, 2, 64);
        d = fminf(fmaxf(d, -10.f), 10.f);
        float ex = __expf(d);
        if ((lane & 3) == 0) attBuf[(size_t)e * HEADS + h] = ex;
        norm += ex;
        acc[0] += ex * bf2f(va.x);
        acc[1] += ex * bf2f(va.y);
        acc[2] += ex * bf2f(va.z);
        acc[3] += ex * bf2f(va.w);
        acc[4] += ex * bf2f(vb.x);
        acc[5] += ex * bf2f(vb.y);
        acc[6] += ex * bf2f(vb.z);
        acc[7] += ex * bf2f(vb.w);
    }

    float inv = 1.f / (norm + 1e-8f);
    if ((lane & 3) == 0) invNorm[(size_t)node * HEADS + h] = inv;
    float* op = out + (size_t)node * DIM + lane * 8;
    *(float4*)(op)     = make_float4(acc[0] * inv, acc[1] * inv,
                                     acc[2] * inv, acc[3] * inv);
    *(float4*)(op + 4) = make_float4(acc[4] * inv, acc[5] * inv,
                                     acc[6] * inv, acc[7] * inv);
}

// ---------------------------------------------------------------------------
// att_scale: attBuf[e][h] *= invNorm[rows[e]][h]   (finishes softmax)
// ---------------------------------------------------------------------------
__global__ __launch_bounds__(256)
void att_scale(float* __restrict__ attBuf, const float* __restrict__ invNorm,
               const int* __restrict__ rows, int E4)
{
    int t = blockIdx.x * 256 + threadIdx.x;
    if (t >= E4) return;
    int e = t >> 2;
    attBuf[t] *= invNorm[(size_t)rows[e] * 4 + (t & 3)];
}

// ---------------------------------------------------------------------------
// kernel_launch
// ws: Qb bf16 [N*128] | KVb bf16 [N*256] | WtHi,WtLo bf16 [3*128*128]*2
//     | invNorm f32 [N*4] | rowPtr[N+1] | blockSums[128] | cursor[N]
//     | perm[E] | colsCSR[E] | degree[N]
// ---------------------------------------------------------------------------
extern "C" void kernel_launch(void* const* d_in, const int* in_sizes, int n_in,
                              void* d_out, int out_size, void* d_ws, size_t ws_size,
                              hipStream_t stream)
{
    const float* emb  = (const float*)d_in[0];
    const float* qW   = (const float*)d_in[1];
    const float* kW   = (const float*)d_in[2];
    const float* vW   = (const float*)d_in[3];
    const int*   rows = (const int*)d_in[4];
    const int*   cols = (const int*)d_in[5];

    const int N = in_sizes[0] / DIM;
    const int E = in_sizes[4];

    float* dout   = (float*)d_out;
    float* outMat = dout;                        // [N,128]
    float* attBuf = dout + (size_t)N * DIM;      // [E,4]

    ushort* Qb   = (ushort*)d_ws;
    ushort* KVb  = Qb + (size_t)N * DIM;
    ushort* WtHi = KVb + (size_t)N * 256;
    ushort* WtLo = WtHi + 3 * DIM * DIM;
    float* invNorm = (float*)(WtLo + 3 * DIM * DIM);
    int* rowPtr    = (int*)(invNorm + (size_t)N * HEADS);
    int* blockSums = rowPtr + (N + 1);
    int* cursor    = blockSums + 128;
    int* perm      = cursor + N;
    int* colsCSR   = perm + E;
    int* degree    = colsCSR + E;

    hipMemsetAsync(degree, 0, (size_t)N * sizeof(int), stream);

    int eblocks = (E + 255) / 256;
    prep<<<192 + eblocks, 256, 0, stream>>>(qW, kW, vW, WtHi, WtLo,
                                            rows, degree, E);

    dim3 ggrid((N + 63) / 64, 2);
    qkv_fused<<<ggrid, 256, 0, stream>>>(emb, WtHi, WtLo, Qb, KVb, N);

    int nb = (N + 1023) / 1024;
    scanA<<<nb, 256, 0, stream>>>(degree, rowPtr, blockSums, N);
    scanB<<<1, 256, 0, stream>>>(blockSums, nb);
    scanC<<<nb, 256, 0, stream>>>(rowPtr, blockSums, cursor, N, E);

    fill_perm<<<eblocks, 256, 0, stream>>>(rows, cols, cursor, perm, colsCSR, E);

    int gblocks = (N * 16 + 255) / 256;
    csr_fused<<<gblocks, 256, 0, stream>>>(Qb, KVb, rowPtr, perm, colsCSR,
                                           attBuf, invNorm, outMat, N);

    int sblocks = (E * HEADS + 255) / 256;
    att_scale<<<sblocks, 256, 0, stream>>>(attBuf, invNorm, rows, E * HEADS);
}